// Round 7
// baseline (198.911 us; speedup 1.0000x reference)
//
#include <hip/hip_runtime.h>

// out[b,o,n] = sum_{i,k} x[b,i,4n+k] * w[o,i,4n+k] / sqrt(128)
// x: (64,128,4096) f32, w: (128,128,4096) f32, out: (64,128,1024) f32.
//
// Round-7: TWO-PASS. Theory: all single-pass kernels (r1-r6, invariant
// ~165us) die on 16KB-strided row gathers -> one L1 set (bits [11:7]
// constant) -> set thrash + MSHR serialization. Pass 1 streams x,w
// contiguously, packs bf16 into GEMM-native layout in d_ws:
//   Xp[ng 128][i 128][b 64][nk 32]          (64 MB)
//   Wp[ng*2+oh][i 128][o' 64][nk 32]        (128 MB)
// Pass 2 GEMM reads fully-contiguous 32KB slabs per chunk (no strided
// gathers anywhere), r6's proven swizzle + pinned-async pipeline.
// NB=8 n per ng; 128 ngs x 2 o-halves = 256 blocks, 64KB LDS -> 2 blk/CU.

#define CIN  128
#define COUT 128
#define ODIM 1024
#define DDIM 4096
#define NGS   128                 // d = ng*32 + n*4 + k, n in [0,8)
#define NGSTR 262144              // 128*64*32 shorts per ng-plane
#define XP_SHORTS (NGS * NGSTR)           // 33554432 (64 MB)
#define WP_SHORTS (2 * NGS * NGSTR)       // 67108864 (128 MB)
#define WS_NEED   ((size_t)(XP_SHORTS + WP_SHORTS) * 2)   // 192 MB

typedef short bf16x8 __attribute__((ext_vector_type(8)));
typedef short s16x8  __attribute__((ext_vector_type(8)));
typedef short s16x4  __attribute__((ext_vector_type(4)));
typedef float f32x4  __attribute__((ext_vector_type(4)));

static __device__ __forceinline__ unsigned short f2bf(float f) {
    unsigned int u = __float_as_uint(f);
    u += 0x7fffu + ((u >> 16) & 1u);   // RNE fp32 -> bf16
    return (unsigned short)(u >> 16);
}
static __device__ __forceinline__ s16x4 cvt4(float4 v) {
    s16x4 s;
    s[0] = (short)f2bf(v.x); s[1] = (short)f2bf(v.y);
    s[2] = (short)f2bf(v.z); s[3] = (short)f2bf(v.w);
    return s;
}

#define GLD(dst, off, base) \
    asm volatile("global_load_dwordx4 %0, %1, %2" : "=v"(dst) : "v"(off), "s"(base))

// ---------------- Pass 1: pack x,w -> bf16 GEMM-native layout ----------------
// One wave per (row, i): rows 0..8191 = x (b,i), 8192..24575 = w (o,i).
// Reads contiguous 1KB/wave-instruction; writes 64B runs.
__global__ __launch_bounds__(512, 4)
void pack_kernel(const float* __restrict__ xg, const float* __restrict__ wg,
                 short* __restrict__ Xp, short* __restrict__ Wp) {
    const int W    = blockIdx.x * 8 + (threadIdx.x >> 6);
    const int lane = threadIdx.x & 63;

    const float* src;
    short* dst0;
    int ngstride;
    if (W < 8192) {                       // x row: b = W>>7, i = W&127
        src = xg + (size_t)W * DDIM;
        dst0 = Xp + (W & 127) * 2048 + (W >> 7) * 32;
        ngstride = NGSTR;
    } else {
        const int W2 = W - 8192;          // w row: o = W2>>7, i = W2&127
        const int o = W2 >> 7, i = W2 & 127;
        src = wg + (size_t)W2 * DDIM;
        dst0 = Wp + (o >> 6) * NGSTR + i * 2048 + (o & 63) * 32;
        ngstride = 2 * NGSTR;
    }
    const float4* s4 = reinterpret_cast<const float4*>(src);
#pragma unroll
    for (int rep = 0; rep < 16; ++rep) {
        const int d4 = rep * 64 + lane;   // float4 index in row
        float4 v = s4[d4];
        const int ng = d4 >> 3, n = d4 & 7;
        *reinterpret_cast<s16x4*>(dst0 + (size_t)ng * ngstride + n * 4) = cvt4(v);
    }
}

// ---------------- Pass 2: GEMM on packed layout ----------------
// Block: ng x o-half. Out tile 64b x 64o x 8n. 16 chunks of 8 i (K=32).
// LDS per operand: [row 64][i 8][slot 8] 8B units, slot = n ^ (row&7).
__global__ __launch_bounds__(512, 4)
void gemm2_kernel(const short* __restrict__ Xp, const short* __restrict__ Wp,
                  float* __restrict__ outg) {
    __shared__ short xs[64 * 256];   // 32 KB
    __shared__ short ws2[64 * 256];  // 32 KB

    const int bid  = blockIdx.x;
    const int gidx = (bid & 7) * 32 + (bid >> 3);   // XCD-contiguous
    const int ng   = gidx >> 1;                      // 0..127
    const int oh   = gidx & 1;                       // o-half (pair same XCD)

    const int t    = threadIdx.x;
    const int lane = t & 63;
    const int wave = t >> 6;
    const int bt   = wave & 3;        // b 16-row tile
    const int ot   = wave >> 2;       // o 32-col tile
    const int r16  = lane & 15;
    const int kg   = lane >> 4;

    const short* xb = Xp + (size_t)ng * NGSTR;
    const short* wb = Wp + (size_t)(ng * 2 + oh) * NGSTR;

    // staging decode: thread t handles 16B = (row, i, n-pair) per it
    const int srow = (t >> 2) & 63;
    const int sn0  = (t & 3) * 2;
    const int sib  = t >> 8;                  // i = it*2 + sib
    const int sb7  = srow & 7;
    const int ss0  = sn0 ^ sb7;               // slot of lower half (n0 even)
    const unsigned tb = (unsigned)t * 16u;    // byte offset within slab

    f32x4 acc[2][8];
#pragma unroll
    for (int j = 0; j < 2; ++j)
#pragma unroll
        for (int n = 0; n < 8; ++n) acc[j][n] = (f32x4){0.f, 0.f, 0.f, 0.f};

    s16x8 px0, px1, px2, px3, pw0, pw1, pw2, pw3;

#define ISSUE_X(c) do { unsigned _o = tb + (unsigned)(c) * 32768u;           \
    GLD(px0, _o, xb); GLD(px1, _o + 8192u, xb);                              \
    GLD(px2, _o + 16384u, xb); GLD(px3, _o + 24576u, xb); } while (0)
#define ISSUE_W(c) do { unsigned _o = tb + (unsigned)(c) * 32768u;           \
    GLD(pw0, _o, wb); GLD(pw1, _o + 8192u, wb);                              \
    GLD(pw2, _o + 16384u, wb); GLD(pw3, _o + 24576u, wb); } while (0)

#define ST1(arr, v, it) do {                                                 \
    const int _a = srow * 256 + ((it) * 2 + sib) * 32 + ss0 * 4;             \
    const int _b = srow * 256 + ((it) * 2 + sib) * 32 + (ss0 ^ 1) * 4;       \
    *reinterpret_cast<s16x4*>(&arr[_a]) =                                    \
        __builtin_shufflevector(v, v, 0, 1, 2, 3);                           \
    *reinterpret_cast<s16x4*>(&arr[_b]) =                                    \
        __builtin_shufflevector(v, v, 4, 5, 6, 7);                           \
    } while (0)
#define STX() do { ST1(xs, px0, 0); ST1(xs, px1, 1); ST1(xs, px2, 2); ST1(xs, px3, 3); } while (0)
#define STW() do { ST1(ws2, pw0, 0); ST1(ws2, pw1, 1); ST1(ws2, pw2, 2); ST1(ws2, pw3, 3); } while (0)

#define VMW4() do { asm volatile("s_waitcnt vmcnt(4)" ::: "memory");         \
                    __builtin_amdgcn_sched_barrier(0); } while (0)
#define VMW0() do { asm volatile("s_waitcnt vmcnt(0)" ::: "memory");         \
                    __builtin_amdgcn_sched_barrier(0); } while (0)

    const int xrow  = (bt * 16 + r16) * 256;
    const int orow0 = (ot * 32 + r16) * 256;
    const int orow1 = (ot * 32 + 16 + r16) * 256;
    const int rb7   = r16 & 7;                // (row&7) for all three rows
    const int kgo   = kg * 64;                // i-pair base (2kg)*32 shorts

    ISSUE_X(0); ISSUE_W(0);
#pragma unroll 1
    for (int c = 0; c < 16; ++c) {
        VMW4();                           // x(c) arrived (w(c) outstanding)
        STX();
        if (c + 1 < 16) ISSUE_X(c + 1);
        if (c + 1 < 16) { VMW4(); }       // w(c) arrived, x(c+1) in flight
        else            { VMW0(); }
        STW();
        if (c + 1 < 16) ISSUE_W(c + 1);
        asm volatile("s_waitcnt lgkmcnt(0)" ::: "memory");
        __builtin_amdgcn_sched_barrier(0);
        __builtin_amdgcn_s_barrier();

#pragma unroll
        for (int n = 0; n < 8; ++n) {
            const int so = (n ^ rb7) * 4;
            s16x4 a0 = *reinterpret_cast<const s16x4*>(&xs[xrow + kgo + so]);
            s16x4 a1 = *reinterpret_cast<const s16x4*>(&xs[xrow + kgo + 32 + so]);
            s16x4 b0 = *reinterpret_cast<const s16x4*>(&ws2[orow0 + kgo + so]);
            s16x4 b1 = *reinterpret_cast<const s16x4*>(&ws2[orow0 + kgo + 32 + so]);
            s16x4 c0 = *reinterpret_cast<const s16x4*>(&ws2[orow1 + kgo + so]);
            s16x4 c1 = *reinterpret_cast<const s16x4*>(&ws2[orow1 + kgo + 32 + so]);
            bf16x8 A  = __builtin_shufflevector(a0, a1, 0, 1, 2, 3, 4, 5, 6, 7);
            bf16x8 B0 = __builtin_shufflevector(b0, b1, 0, 1, 2, 3, 4, 5, 6, 7);
            bf16x8 B1 = __builtin_shufflevector(c0, c1, 0, 1, 2, 3, 4, 5, 6, 7);
            acc[0][n] = __builtin_amdgcn_mfma_f32_16x16x32_bf16(A, B0, acc[0][n], 0, 0, 0);
            acc[1][n] = __builtin_amdgcn_mfma_f32_16x16x32_bf16(A, B1, acc[1][n], 0, 0, 0);
        }
        if (c + 1 < 16) __builtin_amdgcn_s_barrier();   // LDS reuse guard
    }

    // epilogue: col = o-local (r16), row = b-local (kg*4+reg)
    const float scale = 0.08838834764831845f;  // 1/sqrt(128)
#pragma unroll
    for (int osub = 0; osub < 2; ++osub) {
        const int o = oh * 64 + ot * 32 + osub * 16 + r16;
#pragma unroll
        for (int r = 0; r < 4; ++r) {
            const int b = bt * 16 + kg * 4 + r;
            float* op = outg + ((size_t)b * COUT + o) * ODIM + ng * 8;
            float4 v0, v1;
            v0.x = acc[osub][0][r] * scale; v0.y = acc[osub][1][r] * scale;
            v0.z = acc[osub][2][r] * scale; v0.w = acc[osub][3][r] * scale;
            v1.x = acc[osub][4][r] * scale; v1.y = acc[osub][5][r] * scale;
            v1.z = acc[osub][6][r] * scale; v1.w = acc[osub][7][r] * scale;
            *reinterpret_cast<float4*>(op)     = v0;
            *reinterpret_cast<float4*>(op + 4) = v1;
        }
    }
}

// ---------------- Fallback (r6 single-pass) if ws too small ----------------
#define RS 512
__global__ __launch_bounds__(512, 4)
void nolc_fallback(const float* __restrict__ xg, const float* __restrict__ wg,
                   float* __restrict__ outg) {
    __shared__ short lds[64 * RS];
    const int bid  = blockIdx.x;
    const int gidx = (bid & 7) * 64 + (bid >> 3);
    const int ng   = gidx >> 3;
    const int bq   = (gidx >> 2) & 1;
    const int oq   = gidx & 3;
    const int t = threadIdx.x, lane = t & 63, wave = t >> 6;
    const int sn = t & 15, si = (t >> 4) & 7, rl = t >> 7;
    const float* px = xg + ((size_t)(bq * 32 + rl) * CIN + si) * DDIM + ng * 64 + sn * 4;
    const float* pw = wg + ((size_t)(oq * 32 + rl) * CIN + si) * DDIM + ng * 64 + sn * 4;
    const size_t R4 = (size_t)4 * CIN * DDIM, CH = (size_t)8 * DDIM;
    const int bt = wave & 1, ot = (wave >> 1) & 1, nh = wave >> 2;
    const int r16 = lane & 15, kg = lane >> 4;
    f32x4 acc[8];
#pragma unroll
    for (int n = 0; n < 8; ++n) acc[n] = (f32x4){0.f, 0.f, 0.f, 0.f};
    const int xbase = (bt * 16 + r16) * RS, wbase = (32 + ot * 16 + r16) * RS;
#pragma unroll 1
    for (int c = 0; c < 16; ++c) {
        float4 rx[8], rw[8];
#pragma unroll
        for (int it = 0; it < 8; ++it) {
            rx[it] = *reinterpret_cast<const float4*>(px + c * CH + it * R4);
            rw[it] = *reinterpret_cast<const float4*>(pw + c * CH + it * R4);
        }
#pragma unroll
        for (int it = 0; it < 8; ++it) {
            const int row = it * 4 + rl;
            *reinterpret_cast<s16x4*>(&lds[row * RS + si * 64 + ((sn ^ (row & 15)) << 2)]) = cvt4(rx[it]);
            const int row2 = 32 + it * 4 + rl;
            *reinterpret_cast<s16x4*>(&lds[row2 * RS + si * 64 + ((sn ^ (row2 & 15)) << 2)]) = cvt4(rw[it]);
        }
        __syncthreads();
#pragma unroll
        for (int nn = 0; nn < 8; ++nn) {
            const int n = nh * 8 + nn, so = (n ^ r16) << 2;
            s16x4 a0 = *reinterpret_cast<const s16x4*>(&lds[xbase + (kg * 2) * 64 + so]);
            s16x4 a1 = *reinterpret_cast<const s16x4*>(&lds[xbase + (kg * 2 + 1) * 64 + so]);
            s16x4 b0 = *reinterpret_cast<const s16x4*>(&lds[wbase + (kg * 2) * 64 + so]);
            s16x4 b1 = *reinterpret_cast<const s16x4*>(&lds[wbase + (kg * 2 + 1) * 64 + so]);
            bf16x8 A = __builtin_shufflevector(a0, a1, 0, 1, 2, 3, 4, 5, 6, 7);
            bf16x8 B = __builtin_shufflevector(b0, b1, 0, 1, 2, 3, 4, 5, 6, 7);
            acc[nn] = __builtin_amdgcn_mfma_f32_16x16x32_bf16(A, B, acc[nn], 0, 0, 0);
        }
        if (c + 1 < 16) __syncthreads();
    }
    const float scale = 0.08838834764831845f;
    const int o = oq * 32 + ot * 16 + r16;
#pragma unroll
    for (int r = 0; r < 4; ++r) {
        const int b = bq * 32 + bt * 16 + kg * 4 + r;
        float* op = outg + ((size_t)b * COUT + o) * ODIM + ng * 16 + nh * 8;
        float4 v0, v1;
        v0.x = acc[0][r] * scale; v0.y = acc[1][r] * scale;
        v0.z = acc[2][r] * scale; v0.w = acc[3][r] * scale;
        v1.x = acc[4][r] * scale; v1.y = acc[5][r] * scale;
        v1.z = acc[6][r] * scale; v1.w = acc[7][r] * scale;
        *reinterpret_cast<float4*>(op) = v0;
        *reinterpret_cast<float4*>(op + 4) = v1;
    }
}

extern "C" void kernel_launch(void* const* d_in, const int* in_sizes, int n_in,
                              void* d_out, int out_size, void* d_ws, size_t ws_size,
                              hipStream_t stream) {
    const float* x = (const float*)d_in[0];
    const float* w = (const float*)d_in[1];
    float* out = (float*)d_out;
    if (ws_size >= WS_NEED) {
        short* Xp = (short*)d_ws;
        short* Wp = Xp + XP_SHORTS;
        pack_kernel<<<dim3(3072), dim3(512), 0, stream>>>(x, w, Xp, Wp);
        gemm2_kernel<<<dim3(256), dim3(512), 0, stream>>>(Xp, Wp, out);
    } else {
        nolc_fallback<<<dim3(512), dim3(512), 0, stream>>>(x, w, out);
    }
}